// Round 1
// baseline (643.712 us; speedup 1.0000x reference)
//
#include <hip/hip_runtime.h>

// Problem constants (from reference setup_inputs): B=4, T=512, U=128, D=512, V=512
#define B_ 4
#define T_ 512
#define U_ 128
#define D_ 512
#define V_ 512
#define MS (B_ * T_)          // 2048 speech rows
#define MT (B_ * U_)          // 512 text rows
#define MTOT (MS + MT)        // 2560
#define LOGITS_ELEMS ((size_t)B_ * T_ * U_ * V_)   // 134217728

#define TILE 64
#define TILE_K 32
#define LDS_STRIDE 36         // 32 + 4 pad: keeps float4 alignment, breaks pow2 stride

// Kernel 1: C = X * W^T for X = concat(speech [2048,512], text [512,512]).
// Speech rows -> S (no bias), text rows -> Tx (+bias).
__global__ __launch_bounds__(256, 2) void gemm_joint(
    const float* __restrict__ speech, const float* __restrict__ text,
    const float* __restrict__ W, const float* __restrict__ bias,
    float* __restrict__ S, float* __restrict__ Tx)
{
    __shared__ float Xs[TILE * LDS_STRIDE];
    __shared__ float Ws[TILE * LDS_STRIDE];

    const int tid = threadIdx.x;
    const int m0 = blockIdx.x * TILE;
    const int n0 = blockIdx.y * TILE;
    const int tx = tid & 15;       // 16 cols of threads
    const int ty = tid >> 4;       // 16 rows of threads

    float acc[4][4] = {};

    for (int k0 = 0; k0 < D_; k0 += TILE_K) {
        // Stage 64x32 tiles of X and W: 512 float4 each, 2 per thread.
        #pragma unroll
        for (int i = 0; i < 2; ++i) {
            const int f4  = tid + i * 256;
            const int row = f4 >> 3;          // 8 float4 per 32-wide row
            const int col = (f4 & 7) * 4;
            const int m = m0 + row;
            const float* src = (m < MS) ? (speech + (size_t)m * D_)
                                        : (text + (size_t)(m - MS) * D_);
            *(float4*)(&Xs[row * LDS_STRIDE + col]) =
                *(const float4*)(src + k0 + col);
            *(float4*)(&Ws[row * LDS_STRIDE + col]) =
                *(const float4*)(W + (size_t)(n0 + row) * D_ + k0 + col);
        }
        __syncthreads();

        #pragma unroll
        for (int kk = 0; kk < TILE_K; kk += 4) {
            float4 a[4], b[4];
            #pragma unroll
            for (int i = 0; i < 4; ++i)
                a[i] = *(const float4*)(&Xs[(ty * 4 + i) * LDS_STRIDE + kk]);
            #pragma unroll
            for (int j = 0; j < 4; ++j)
                b[j] = *(const float4*)(&Ws[(tx * 4 + j) * LDS_STRIDE + kk]);
            #pragma unroll
            for (int i = 0; i < 4; ++i) {
                #pragma unroll
                for (int j = 0; j < 4; ++j) {
                    acc[i][j] += a[i].x * b[j].x;
                    acc[i][j] += a[i].y * b[j].y;
                    acc[i][j] += a[i].z * b[j].z;
                    acc[i][j] += a[i].w * b[j].w;
                }
            }
        }
        __syncthreads();
    }

    // Epilogue: float4 stores; fold bias into the text rows (Tx).
    const int vbase = n0 + tx * 4;
    #pragma unroll
    for (int i = 0; i < 4; ++i) {
        const int m = m0 + ty * 4 + i;
        float4 o;
        o.x = acc[i][0]; o.y = acc[i][1]; o.z = acc[i][2]; o.w = acc[i][3];
        if (m < MS) {
            *(float4*)(S + (size_t)m * V_ + vbase) = o;
        } else {
            o.x += bias[vbase + 0];
            o.y += bias[vbase + 1];
            o.z += bias[vbase + 2];
            o.w += bias[vbase + 3];
            *(float4*)(Tx + (size_t)(m - MS) * V_ + vbase) = o;
        }
    }
}

// Kernel 2: out[b,t,u,v] = S[b*T+t, v] + Tx[b*U+u, v]   (bias already in Tx)
// One block per (b,t): writes a contiguous 64K-float region, float4-coalesced.
__global__ __launch_bounds__(256) void bcast_add(
    const float* __restrict__ S, const float* __restrict__ Tx,
    float* __restrict__ out)
{
    const int V4 = V_ / 4;                  // 128
    const int bt = blockIdx.x;              // 0..2047
    const int b  = bt >> 9;                 // bt / T_
    const int tid = threadIdx.x;

    const float4* S4 = (const float4*)S + (size_t)bt * V4;
    const float4* T4 = (const float4*)Tx + (size_t)b * U_ * V4;
    float4* O4 = (float4*)out + (size_t)bt * U_ * V4;

    // idx % 128 == tid % 128 for every iteration -> S row element is loop-invariant
    const float4 sv = S4[tid & (V4 - 1)];

    #pragma unroll 4
    for (int idx = tid; idx < U_ * V4; idx += 256) {
        float4 tv = T4[idx];
        float4 o;
        o.x = sv.x + tv.x;
        o.y = sv.y + tv.y;
        o.z = sv.z + tv.z;
        o.w = sv.w + tv.w;
        O4[idx] = o;
    }
}

// Kernel 3: append speech_len / text_len as floats after the logits.
__global__ void copy_lens(const int* __restrict__ sl, const int* __restrict__ tl,
                          float* __restrict__ out)
{
    const int i = threadIdx.x;
    if (i < B_)            out[LOGITS_ELEMS + i] = (float)sl[i];
    else if (i < 2 * B_)   out[LOGITS_ELEMS + i] = (float)tl[i - B_];
}

extern "C" void kernel_launch(void* const* d_in, const int* in_sizes, int n_in,
                              void* d_out, int out_size, void* d_ws, size_t ws_size,
                              hipStream_t stream) {
    const float* speech = (const float*)d_in[0];
    const float* text   = (const float*)d_in[1];
    const float* W      = (const float*)d_in[2];
    const float* bias   = (const float*)d_in[3];
    const int*   sl     = (const int*)d_in[4];
    const int*   tl     = (const int*)d_in[5];
    float* out = (float*)d_out;

    float* S  = (float*)d_ws;                 // [2048, 512]  (4 MB)
    float* Tx = S + (size_t)MS * V_;          // [512, 512]   (1 MB)

    dim3 g1(MTOT / TILE, V_ / TILE);          // 40 x 8 = 320 blocks
    gemm_joint<<<g1, 256, 0, stream>>>(speech, text, W, bias, S, Tx);

    bcast_add<<<MS, 256, 0, stream>>>(S, Tx, out);   // 2048 blocks

    copy_lens<<<1, 64, 0, stream>>>(sl, tl, out);
}